// Round 2
// baseline (6983.526 us; speedup 1.0000x reference)
//
#include <hip/hip_runtime.h>
#include <hip/hip_bf16.h>
#include <cstddef>

#define BB 8
#define CC 512
#define NN 4096
#define CQ 64

static __device__ __forceinline__ float bf2f(__hip_bfloat16 v){ return __bfloat162float(v); }
static __device__ __forceinline__ __hip_bfloat16 f2bf(float v){ return __float2bfloat16(v); }

// fp32 -> bf16 bits, round-to-nearest-even
static __device__ __forceinline__ unsigned bf16_bits(float f){
  unsigned u = __float_as_uint(f);
  u += 0x7fffu + ((u >> 16) & 1u);
  return u >> 16;
}
static __device__ __forceinline__ unsigned pack2bf(float lo, float hi){
  return bf16_bits(lo) | (bf16_bits(hi) << 16);
}
static __device__ __forceinline__ float unpack_lo(unsigned u){ return __uint_as_float(u << 16); }
static __device__ __forceinline__ float unpack_hi(unsigned u){ return __uint_as_float(u & 0xffff0000u); }

// ---- Q,K projections: Q[b][n][o] (fp32), K[b][o][n] (fp32) ----
__global__ __launch_bounds__(256) void proj_qk_kernel(
    const float* __restrict__ x, const float* __restrict__ Wq,
    const float* __restrict__ Wk,
    const float* __restrict__ bq, const float* __restrict__ bk,
    float* __restrict__ Q, float* __restrict__ K){
  const int n  = blockIdx.x*256 + threadIdx.x;
  const int og = blockIdx.y*16;
  const int b  = blockIdx.z;
  const float* xb = x + ((size_t)b*CC)*NN + n;
  float accq[16], acck[16];
#pragma unroll
  for (int oi=0;oi<16;++oi){ accq[oi]=0.f; acck[oi]=0.f; }
  for (int c=0;c<CC;++c){
    const float xv = xb[(size_t)c*NN];
#pragma unroll
    for (int oi=0;oi<16;++oi){
      accq[oi] = fmaf(Wq[(og+oi)*CC + c], xv, accq[oi]);
      acck[oi] = fmaf(Wk[(og+oi)*CC + c], xv, acck[oi]);
    }
  }
#pragma unroll
  for (int oi=0;oi<16;++oi){
    const int o = og + oi;
    Q[((size_t)b*NN + n)*CQ + o] = accq[oi] + bq[o];
    K[((size_t)b*CQ + o)*NN + n] = acck[oi] + bk[o];
  }
}

// ---- V projection: V[b][c][n] (bf16) ----
__global__ __launch_bounds__(256) void proj_v_kernel(
    const float* __restrict__ x, const float* __restrict__ Wv,
    const float* __restrict__ bv, __hip_bfloat16* __restrict__ V){
  const int n  = blockIdx.x*256 + threadIdx.x;
  const int cg = blockIdx.y*32;
  const int b  = blockIdx.z;
  const float* xb = x + ((size_t)b*CC)*NN + n;
  float acc[32];
#pragma unroll
  for (int ci=0;ci<32;++ci) acc[ci]=0.f;
  for (int c=0;c<CC;++c){
    const float xv = xb[(size_t)c*NN];
#pragma unroll
    for (int ci=0;ci<32;++ci)
      acc[ci] = fmaf(Wv[(cg+ci)*CC + c], xv, acc[ci]);
  }
#pragma unroll
  for (int ci=0;ci<32;++ci){
    const int c = cg + ci;
    V[((size_t)b*CC + c)*NN + n] = f2bf(acc[ci] + bv[c]);
  }
}

// ---- attention: one block per (b, 8 rows i). Full-row softmax in LDS (bf16-packed),
// then out[c][i] = sum_j p[i][j] V[c][j], residual + gamma. ----
__global__ __launch_bounds__(256) void attn_kernel(
    const float* __restrict__ Q, const float* __restrict__ K,
    const __hip_bfloat16* __restrict__ V, const float* __restrict__ x,
    const float* __restrict__ gamma, float* __restrict__ out){
  // 64 KiB LDS: phase 1 aliases the front as q rows (8x64 f32 = 512 floats)
  // + reduction scratch (redm 32, reds 32). Phase 2 holds p packed bf16x2:
  // ppack[rp][j], rp = row/2, 4*4096 dwords.
  __shared__ unsigned ppack[4*NN];
  float* qsm = (float*)ppack;
  const int tid  = threadIdx.x;
  const int lane = tid & 63;
  const int wid  = tid >> 6;
  const int b    = blockIdx.y;
  const int i0   = blockIdx.x * 8;

  // load 8 q rows (512 floats)
  {
    int i = tid;
    qsm[i] = Q[((size_t)b*NN + i0 + (i>>6))*CQ + (i&63)];
    i = tid + 256;
    qsm[i] = Q[((size_t)b*NN + i0 + (i>>6))*CQ + (i&63)];
  }
  __syncthreads();

  // ---- phase 1: e[r][t] for column j = tid + 256*t ----
  float e[8][16];
#pragma unroll
  for (int r=0;r<8;++r)
#pragma unroll
    for (int t=0;t<16;++t) e[r][t] = 0.f;

  const float* Kb = K + (size_t)b*CQ*NN + tid;
  for (int o=0;o<CQ;++o){
    float qv[8];
#pragma unroll
    for (int r=0;r<8;++r) qv[r] = qsm[r*64 + o];
    const float* Krow = Kb + (size_t)o*NN;
#pragma unroll
    for (int t=0;t<16;++t){
      const float kv = Krow[t*256];
#pragma unroll
      for (int r=0;r<8;++r) e[r][t] = fmaf(qv[r], kv, e[r][t]);
    }
  }

  float* redm = qsm + 512;
  float* reds = qsm + 544;

  // ---- softmax: block max per row ----
  float mm[8];
#pragma unroll
  for (int r=0;r<8;++r){
    float m_ = -3.0e38f;
#pragma unroll
    for (int t=0;t<16;++t) m_ = fmaxf(m_, e[r][t]);
#pragma unroll
    for (int off=32; off>0; off>>=1) m_ = fmaxf(m_, __shfl_xor(m_, off, 64));
    mm[r] = m_;
  }
  if (lane == 0){
#pragma unroll
    for (int r=0;r<8;++r) redm[wid*8+r] = mm[r];
  }
  __syncthreads();
#pragma unroll
  for (int r=0;r<8;++r)
    mm[r] = fmaxf(fmaxf(redm[r], redm[8+r]), fmaxf(redm[16+r], redm[24+r]));

  // ---- exp + block sum ----
  float ss[8];
#pragma unroll
  for (int r=0;r<8;++r){
    float s = 0.f;
#pragma unroll
    for (int t=0;t<16;++t){ const float pv = __expf(e[r][t] - mm[r]); e[r][t] = pv; s += pv; }
#pragma unroll
    for (int off=32; off>0; off>>=1) s += __shfl_xor(s, off, 64);
    ss[r] = s;
  }
  if (lane == 0){
#pragma unroll
    for (int r=0;r<8;++r) reds[wid*8+r] = ss[r];
  }
  __syncthreads();
  float inv[8];
#pragma unroll
  for (int r=0;r<8;++r)
    inv[r] = 1.0f / (reds[r] + reds[8+r] + reds[16+r] + reds[24+r]);
  __syncthreads();   // all reads of q/redm/reds done before ppack overwrites them

  // ---- store normalized p (bf16x2: rows 2rp, 2rp+1) ----
#pragma unroll
  for (int rp=0;rp<4;++rp)
#pragma unroll
    for (int t=0;t<16;++t){
      const int j = tid + t*256;
      ppack[rp*NN + j] = pack2bf(e[2*rp][t]*inv[2*rp], e[2*rp+1][t]*inv[2*rp+1]);
    }
  __syncthreads();

  // ---- phase 2: out[c][i0+r] = sum_j p[r][j] * V[c][j]; wave owns 128 channels ----
  const __hip_bfloat16* Vb = V + (size_t)b*CC*NN;
  const float gam = gamma[0];
  for (int cg=0; cg<16; ++cg){
    const int c0 = wid*128 + cg*8;
    float acc[8][8];
#pragma unroll
    for (int ci=0;ci<8;++ci)
#pragma unroll
      for (int r=0;r<8;++r) acc[ci][r] = 0.f;
    for (int t=0;t<64;++t){
      const int j = (t<<6) | lane;
      const unsigned u0 = ppack[j], u1 = ppack[NN+j], u2 = ppack[2*NN+j], u3 = ppack[3*NN+j];
      const float p0 = unpack_lo(u0), p1 = unpack_hi(u0);
      const float p2 = unpack_lo(u1), p3 = unpack_hi(u1);
      const float p4 = unpack_lo(u2), p5 = unpack_hi(u2);
      const float p6 = unpack_lo(u3), p7 = unpack_hi(u3);
#pragma unroll
      for (int ci=0;ci<8;++ci){
        const float vf = bf2f(Vb[(size_t)(c0+ci)*NN + j]);
        acc[ci][0] = fmaf(vf, p0, acc[ci][0]);
        acc[ci][1] = fmaf(vf, p1, acc[ci][1]);
        acc[ci][2] = fmaf(vf, p2, acc[ci][2]);
        acc[ci][3] = fmaf(vf, p3, acc[ci][3]);
        acc[ci][4] = fmaf(vf, p4, acc[ci][4]);
        acc[ci][5] = fmaf(vf, p5, acc[ci][5]);
        acc[ci][6] = fmaf(vf, p6, acc[ci][6]);
        acc[ci][7] = fmaf(vf, p7, acc[ci][7]);
      }
    }
#pragma unroll
    for (int ci=0;ci<8;++ci){
#pragma unroll
      for (int r=0;r<8;++r){
        float s = acc[ci][r];
#pragma unroll
        for (int off=32; off>0; off>>=1) s += __shfl_xor(s, off, 64);
        if (lane == 0){
          const size_t idx = ((size_t)b*CC + (c0+ci))*NN + (i0 + r);
          out[idx] = fmaf(gam, s, x[idx]);
        }
      }
    }
  }
}

extern "C" void kernel_launch(void* const* d_in, const int* in_sizes, int n_in,
                              void* d_out, int out_size, void* d_ws, size_t ws_size,
                              hipStream_t stream){
  const float* x     = (const float*)d_in[0];
  const float* Wq    = (const float*)d_in[1];
  const float* bq    = (const float*)d_in[2];
  const float* Wk    = (const float*)d_in[3];
  const float* bk    = (const float*)d_in[4];
  const float* Wv    = (const float*)d_in[5];
  const float* bv    = (const float*)d_in[6];
  const float* gamma = (const float*)d_in[7];
  float* out = (float*)d_out;

  // workspace: Q fp32 [8,4096,64] 8.39MB; K fp32 [8,64,4096] 8.39MB;
  // V bf16 [8,512,4096] 33.55MB.  total ~50.3 MiB
  float* Qws = (float*)d_ws;
  float* Kws = Qws + (size_t)BB*NN*CQ;
  __hip_bfloat16* Vws = (__hip_bfloat16*)(Kws + (size_t)BB*CQ*NN);

  proj_qk_kernel<<<dim3(NN/256, CQ/16, BB), 256, 0, stream>>>(x, Wq, Wk, bq, bk, Qws, Kws);
  proj_v_kernel<<<dim3(NN/256, CC/32, BB), 256, 0, stream>>>(x, Wv, bv, Vws);
  attn_kernel<<<dim3(NN/8, BB), 256, 0, stream>>>(Qws, Kws, Vws, x, gamma, out);
}

// Round 3
// 1127.878 us; speedup vs baseline: 6.1917x; 6.1917x over previous
//
#include <hip/hip_runtime.h>
#include <hip/hip_bf16.h>
#include <cstddef>

#define BB 8
#define CC 512
#define NN 4096
#define CQ 64
#define MQ 64   // Q-rows per block
#define NJ 64   // j-tile

typedef short bf16x8 __attribute__((ext_vector_type(8)));
typedef float f32x4  __attribute__((ext_vector_type(4)));

// fp32 -> bf16 bits, round-to-nearest-even
static __device__ __forceinline__ unsigned bf16_bits(float f){
  unsigned u = __float_as_uint(f);
  u += 0x7fffu + ((u >> 16) & 1u);
  return u >> 16;
}
static __device__ __forceinline__ unsigned pack2bf(float lo, float hi){
  return bf16_bits(lo) | (bf16_bits(hi) << 16);
}

// ---- Q,K projections -> bf16, layout [b][n][o] (o contiguous, 64 per row) ----
__global__ __launch_bounds__(256) void proj_qk_kernel(
    const float* __restrict__ x, const float* __restrict__ Wq,
    const float* __restrict__ Wk,
    const float* __restrict__ bq, const float* __restrict__ bk,
    short* __restrict__ Qbf, short* __restrict__ Kbf){
  const int n  = blockIdx.x*256 + threadIdx.x;
  const int og = blockIdx.y*16;
  const int b  = blockIdx.z;
  const float* xb = x + ((size_t)b*CC)*NN + n;
  float accq[16], acck[16];
#pragma unroll
  for (int oi=0;oi<16;++oi){ accq[oi]=0.f; acck[oi]=0.f; }
  for (int c=0;c<CC;c+=4){
    const float xv0 = xb[(size_t)c*NN],     xv1 = xb[(size_t)(c+1)*NN];
    const float xv2 = xb[(size_t)(c+2)*NN], xv3 = xb[(size_t)(c+3)*NN];
#pragma unroll
    for (int oi=0;oi<16;++oi){
      const float4 wq = *(const float4*)&Wq[(og+oi)*CC + c];
      const float4 wk = *(const float4*)&Wk[(og+oi)*CC + c];
      accq[oi] = fmaf(wq.x,xv0, fmaf(wq.y,xv1, fmaf(wq.z,xv2, fmaf(wq.w,xv3, accq[oi]))));
      acck[oi] = fmaf(wk.x,xv0, fmaf(wk.y,xv1, fmaf(wk.z,xv2, fmaf(wk.w,xv3, acck[oi]))));
    }
  }
  bf16x8 q0, q1, k0, k1;
#pragma unroll
  for (int oi=0;oi<8;++oi){
    q0[oi] = (short)bf16_bits(accq[oi]   + bq[og+oi]);
    q1[oi] = (short)bf16_bits(accq[8+oi] + bq[og+8+oi]);
    k0[oi] = (short)bf16_bits(acck[oi]   + bk[og+oi]);
    k1[oi] = (short)bf16_bits(acck[8+oi] + bk[og+8+oi]);
  }
  short* qp = Qbf + ((size_t)b*NN + n)*CQ + og;
  short* kp = Kbf + ((size_t)b*NN + n)*CQ + og;
  *(bf16x8*)qp = q0; *(bf16x8*)(qp+8) = q1;
  *(bf16x8*)kp = k0; *(bf16x8*)(kp+8) = k1;
}

// ---- V projection -> bf16, layout [b][c][n] ----
__global__ __launch_bounds__(256) void proj_v_kernel(
    const float* __restrict__ x, const float* __restrict__ Wv,
    const float* __restrict__ bv, short* __restrict__ Vbf){
  const int n  = blockIdx.x*256 + threadIdx.x;
  const int cg = blockIdx.y*32;
  const int b  = blockIdx.z;
  const float* xb = x + ((size_t)b*CC)*NN + n;
  float acc[32];
#pragma unroll
  for (int ci=0;ci<32;++ci) acc[ci]=0.f;
  for (int c=0;c<CC;c+=4){
    const float xv0 = xb[(size_t)c*NN],     xv1 = xb[(size_t)(c+1)*NN];
    const float xv2 = xb[(size_t)(c+2)*NN], xv3 = xb[(size_t)(c+3)*NN];
#pragma unroll
    for (int ci=0;ci<32;++ci){
      const float4 wv = *(const float4*)&Wv[(cg+ci)*CC + c];
      acc[ci] = fmaf(wv.x,xv0, fmaf(wv.y,xv1, fmaf(wv.z,xv2, fmaf(wv.w,xv3, acc[ci]))));
    }
  }
#pragma unroll
  for (int ci=0;ci<32;++ci){
    const int c = cg + ci;
    Vbf[((size_t)b*CC + c)*NN + n] = (short)bf16_bits(acc[ci] + bv[c]);
  }
}

// ---- MFMA flash attention (no max-subtraction; exp/sum + divide at end) ----
// Block: 256 thr (4 waves), MQ=64 q-rows. Wave w: S^T j-sub w (16 j) x 4 i-subs;
// PV: c in [w*128, w*128+128). O^T accumulated in regs (D: row=c, col=i).
__global__ __launch_bounds__(256, 2) void attn_mfma_kernel(
    const short* __restrict__ Qbf, const short* __restrict__ Kbf,
    const short* __restrict__ Vbf, const float* __restrict__ x,
    const float* __restrict__ gamma, float* __restrict__ out){
  // P~ tile in LDS: [MQ rows i][64 j] bf16, row stride 36 dwords (=72 bf16, +16B pad)
  __shared__ unsigned plds[MQ * 36];
  __shared__ float lsum[4][MQ];

  const int tid  = threadIdx.x;
  const int lane = tid & 63;
  const int w    = tid >> 6;
  const int iq   = lane & 15;     // fragment row/col index
  const int q    = lane >> 4;     // quad
  const int bid  = blockIdx.x;
  const int b    = bid & 7;       // XCD-batch swizzle: XCD k works batch k
  const int i0   = (bid >> 3) * MQ;

  // Q B-frags (persistent): qb[s][ks], B[k=o][n=i], i = s*16+iq, o = q*8 + ks*32
  bf16x8 qb[4][2];
#pragma unroll
  for (int s=0;s<4;++s){
    const short* qp = Qbf + ((size_t)b*NN + i0 + s*16 + iq)*CQ + q*8;
#pragma unroll
    for (int ks=0;ks<2;++ks) qb[s][ks] = *(const bf16x8*)(qp + ks*32);
  }

  f32x4 acc[8][4];
#pragma unroll
  for (int cs=0;cs<8;++cs)
#pragma unroll
    for (int s=0;s<4;++s) acc[cs][s] = (f32x4){0.f,0.f,0.f,0.f};
  float lpart[4] = {0.f,0.f,0.f,0.f};

  const short* Kbase = Kbf + ((size_t)b*NN + w*16 + iq)*CQ + q*8;   // A[m=j][k=o]
  const short* Vbase = Vbf + ((size_t)b*CC + w*128 + iq)*NN + q*8;  // A[m=c][k=j]

  for (int jt=0; jt<NN/NJ; ++jt){
    const int j0 = jt*NJ;
    // ---- S^T = K . Q^T for this wave's 16 j rows ----
    const short* kp = Kbase + (size_t)j0*CQ;
    const bf16x8 ka0 = *(const bf16x8*)kp;
    const bf16x8 ka1 = *(const bf16x8*)(kp + 32);
    f32x4 sf[4];
#pragma unroll
    for (int s=0;s<4;++s){
      sf[s] = __builtin_amdgcn_mfma_f32_16x16x32_bf16(ka0, qb[s][0], (f32x4){0.f,0.f,0.f,0.f}, 0,0,0);
      sf[s] = __builtin_amdgcn_mfma_f32_16x16x32_bf16(ka1, qb[s][1], sf[s], 0,0,0);
    }
    // ---- exp (no max shift), l partial, pack to LDS: row i, cols j = w*16+q*4.. ----
#pragma unroll
    for (int s=0;s<4;++s){
      const float p0 = __expf(sf[s][0]);
      const float p1 = __expf(sf[s][1]);
      const float p2 = __expf(sf[s][2]);
      const float p3 = __expf(sf[s][3]);
      lpart[s] += (p0+p1) + (p2+p3);
      const int row = s*16 + iq;
      plds[row*36 + w*8 + q*2]     = pack2bf(p0, p1);
      plds[row*36 + w*8 + q*2 + 1] = pack2bf(p2, p3);
    }
    __syncthreads();
    // ---- PV: B[k=j][n=i] frags from LDS, A = V rows direct from global ----
    bf16x8 pb[4][2];
#pragma unroll
    for (int s=0;s<4;++s){
      const unsigned* pr = &plds[(s*16 + iq)*36 + q*4];
      pb[s][0] = *(const bf16x8*)pr;
      pb[s][1] = *(const bf16x8*)(pr + 16);
    }
    const short* vp = Vbase + j0;
#pragma unroll
    for (int cs=0;cs<8;++cs){
      const short* vrow = vp + (size_t)cs*16*NN;
      const bf16x8 va0 = *(const bf16x8*)vrow;
      const bf16x8 va1 = *(const bf16x8*)(vrow + 32);
#pragma unroll
      for (int s=0;s<4;++s){
        acc[cs][s] = __builtin_amdgcn_mfma_f32_16x16x32_bf16(va0, pb[s][0], acc[cs][s], 0,0,0);
        acc[cs][s] = __builtin_amdgcn_mfma_f32_16x16x32_bf16(va1, pb[s][1], acc[cs][s], 0,0,0);
      }
    }
    __syncthreads();
  }

  // ---- l reduction: quads within wave, then across waves via LDS ----
#pragma unroll
  for (int s=0;s<4;++s){
    lpart[s] += __shfl_xor(lpart[s], 16, 64);
    lpart[s] += __shfl_xor(lpart[s], 32, 64);
  }
  if (q == 0){
#pragma unroll
    for (int s=0;s<4;++s) lsum[w][s*16 + iq] = lpart[s];
  }
  __syncthreads();
  float linv[4];
#pragma unroll
  for (int s=0;s<4;++s){
    const int i = s*16 + iq;
    linv[s] = 1.0f / (lsum[0][i] + lsum[1][i] + lsum[2][i] + lsum[3][i]);
  }

  // ---- epilogue: out[c][i] = gamma * O^T[c][i]/l[i] + x[c][i] ----
  const float gam = gamma[0];
#pragma unroll
  for (int cs=0;cs<8;++cs){
#pragma unroll
    for (int s=0;s<4;++s){
      const int cb = w*128 + cs*16 + q*4;     // D row = quad*4 + reg
      const int i  = i0 + s*16 + iq;          // D col = lane&15
#pragma unroll
      for (int r=0;r<4;++r){
        const size_t idx = ((size_t)b*CC + cb + r)*NN + i;
        out[idx] = fmaf(gam, acc[cs][s][r]*linv[s], x[idx]);
      }
    }
  }
}

extern "C" void kernel_launch(void* const* d_in, const int* in_sizes, int n_in,
                              void* d_out, int out_size, void* d_ws, size_t ws_size,
                              hipStream_t stream){
  const float* x     = (const float*)d_in[0];
  const float* Wq    = (const float*)d_in[1];
  const float* bq    = (const float*)d_in[2];
  const float* Wk    = (const float*)d_in[3];
  const float* bk    = (const float*)d_in[4];
  const float* Wv    = (const float*)d_in[5];
  const float* bv    = (const float*)d_in[6];
  const float* gamma = (const float*)d_in[7];
  float* out = (float*)d_out;

  // workspace: Qbf [8,4096,64] bf16 4.2MB; Kbf same 4.2MB; Vbf [8,512,4096] bf16 33.6MB
  short* Qbf = (short*)d_ws;
  short* Kbf = Qbf + (size_t)BB*NN*CQ;
  short* Vbf = Kbf + (size_t)BB*NN*CQ;

  proj_qk_kernel<<<dim3(NN/256, CQ/16, BB), 256, 0, stream>>>(x, Wq, Wk, bq, bk, Qbf, Kbf);
  proj_v_kernel<<<dim3(NN/256, CC/32, BB), 256, 0, stream>>>(x, Wv, bv, Vbf);
  attn_mfma_kernel<<<dim3(BB*NN/MQ), 256, 0, stream>>>(Qbf, Kbf, Vbf, x, gamma, out);
}

// Round 4
// 604.583 us; speedup vs baseline: 11.5510x; 1.8655x over previous
//
#include <hip/hip_runtime.h>
#include <hip/hip_bf16.h>
#include <cstddef>

#define BB 8
#define CC 512
#define NN 4096
#define CQ 64
#define MQ 64   // Q-rows per attn block
#define NJ 64   // j-tile

typedef short bf16x8 __attribute__((ext_vector_type(8)));
typedef float f32x4  __attribute__((ext_vector_type(4)));

// fp32 -> bf16 bits, round-to-nearest-even
static __device__ __forceinline__ unsigned bf16_bits(float f){
  unsigned u = __float_as_uint(f);
  u += 0x7fffu + ((u >> 16) & 1u);
  return u >> 16;
}
static __device__ __forceinline__ unsigned pack2bf(float lo, float hi){
  return bf16_bits(lo) | (bf16_bits(hi) << 16);
}

// ---- weights fp32 -> bf16 (Wqk packed: rows 0..63 = Wq, 64..127 = Wk) ----
__global__ __launch_bounds__(256) void cvt_w_kernel(
    const float* __restrict__ Wq, const float* __restrict__ Wk,
    const float* __restrict__ Wv,
    short* __restrict__ Wqkbf, short* __restrict__ Wvbf){
  const int i = blockIdx.x*256 + threadIdx.x;
  if (i < CQ*CC){
    Wqkbf[i]         = (short)bf16_bits(Wq[i]);
    Wqkbf[CQ*CC + i] = (short)bf16_bits(Wk[i]);
  }
  Wvbf[i] = (short)bf16_bits(Wv[i]);
}

// ---- x fp32 [b][c][n] -> xT bf16 [b][n][c] via LDS 64x64 tile ----
__global__ __launch_bounds__(256) void cvt_x_kernel(
    const float* __restrict__ x, short* __restrict__ xT){
  __shared__ float lds[64*67];
  const int tid = threadIdx.x;
  const int n0 = blockIdx.x*64, c0 = blockIdx.y*64, b = blockIdx.z;
  const int nl = tid & 63, cw = tid >> 6;
  const float* xp = x + ((size_t)b*CC + c0)*NN + n0;
#pragma unroll
  for (int i=0;i<16;++i){
    const int cl = cw*16 + i;
    lds[nl*67 + cl] = xp[(size_t)cl*NN + nl];
  }
  __syncthreads();
  short* xTp = xT + ((size_t)b*NN + n0)*CC + c0;
#pragma unroll
  for (int p=0;p<2;++p){
    const int nl2 = (tid>>3) + p*32;
    const int c8 = (tid&7)*8;
    const float* r = &lds[nl2*67 + c8];
    uint4 v;
    v.x = pack2bf(r[0], r[1]);
    v.y = pack2bf(r[2], r[3]);
    v.z = pack2bf(r[4], r[5]);
    v.w = pack2bf(r[6], r[7]);
    *(uint4*)&xTp[(size_t)nl2*CC + c8] = v;
  }
}

// ---- Q,K projection via MFMA: D[n][o] = xT . Wqk^T;  Qbf/Kbf layout [b][n][64] ----
__global__ __launch_bounds__(256) void proj_qk_mfma(
    const short* __restrict__ xT, const short* __restrict__ Wqkbf,
    const float* __restrict__ bq, const float* __restrict__ bk,
    short* __restrict__ Qbf, short* __restrict__ Kbf){
  const int tid  = threadIdx.x;
  const int lane = tid & 63;
  const int w    = tid >> 6;
  const int iq   = lane & 15;
  const int q    = lane >> 4;
  const int b    = blockIdx.z;
  const int n0w  = blockIdx.x*128 + w*32;

  f32x4 acc[2][8];
#pragma unroll
  for (int ns=0;ns<2;++ns)
#pragma unroll
    for (int os=0;os<8;++os) acc[ns][os] = (f32x4){0.f,0.f,0.f,0.f};

  const short* Abase = xT + ((size_t)b*NN + n0w + iq)*CC + q*8;
  const short* Bbase = Wqkbf + (size_t)iq*CC + q*8;

  for (int ks=0; ks<16; ++ks){
    const int k = ks*32;
    bf16x8 af[2], bf[8];
#pragma unroll
    for (int ns=0;ns<2;++ns) af[ns] = *(const bf16x8*)(Abase + (size_t)ns*16*CC + k);
#pragma unroll
    for (int os=0;os<8;++os) bf[os] = *(const bf16x8*)(Bbase + (size_t)os*16*CC + k);
#pragma unroll
    for (int ns=0;ns<2;++ns)
#pragma unroll
      for (int os=0;os<8;++os)
        acc[ns][os] = __builtin_amdgcn_mfma_f32_16x16x32_bf16(af[ns], bf[os], acc[ns][os], 0,0,0);
  }
#pragma unroll
  for (int ns=0;ns<2;++ns){
#pragma unroll
    for (int os=0;os<8;++os){
      const int o = (os&4) ? ((os-4)*16 + iq) : (os*16 + iq);
      const float bias = (os<4) ? bq[o] : bk[o];
      short* dst = (os<4) ? Qbf : Kbf;
#pragma unroll
      for (int r=0;r<4;++r){
        const int n = n0w + ns*16 + q*4 + r;
        dst[((size_t)b*NN + n)*CQ + o] = (short)bf16_bits(acc[ns][os][r] + bias);
      }
    }
  }
}

// ---- V projection via MFMA: D[c][n] = Wv . x;  Vbf layout [b][c][n] ----
__global__ __launch_bounds__(256) void proj_v_mfma(
    const short* __restrict__ xT, const short* __restrict__ Wvbf,
    const float* __restrict__ bv, short* __restrict__ Vbf){
  const int tid  = threadIdx.x;
  const int lane = tid & 63;
  const int w    = tid >> 6;
  const int iq   = lane & 15;
  const int q    = lane >> 4;
  const int b    = blockIdx.z;
  const int c0w  = blockIdx.y*128 + (w&1)*64;
  const int n0w  = blockIdx.x*64 + (w>>1)*32;

  f32x4 acc[4][2];
#pragma unroll
  for (int cs=0;cs<4;++cs)
#pragma unroll
    for (int ns=0;ns<2;++ns) acc[cs][ns] = (f32x4){0.f,0.f,0.f,0.f};

  const short* Abase = Wvbf + (size_t)(c0w + iq)*CC + q*8;
  const short* Bbase = xT + ((size_t)b*NN + n0w + iq)*CC + q*8;

  for (int ks=0; ks<16; ++ks){
    const int k = ks*32;
    bf16x8 af[4], bf[2];
#pragma unroll
    for (int cs=0;cs<4;++cs) af[cs] = *(const bf16x8*)(Abase + (size_t)cs*16*CC + k);
#pragma unroll
    for (int ns=0;ns<2;++ns) bf[ns] = *(const bf16x8*)(Bbase + (size_t)ns*16*CC + k);
#pragma unroll
    for (int cs=0;cs<4;++cs)
#pragma unroll
      for (int ns=0;ns<2;++ns)
        acc[cs][ns] = __builtin_amdgcn_mfma_f32_16x16x32_bf16(af[cs], bf[ns], acc[cs][ns], 0,0,0);
  }
#pragma unroll
  for (int cs=0;cs<4;++cs){
#pragma unroll
    for (int r=0;r<4;++r){
      const int c = c0w + cs*16 + q*4 + r;
      const float bias = bv[c];
#pragma unroll
      for (int ns=0;ns<2;++ns){
        const int n = n0w + ns*16 + iq;
        Vbf[((size_t)b*CC + c)*NN + n] = (short)bf16_bits(acc[cs][ns][r] + bias);
      }
    }
  }
}

// ---- MFMA flash attention (no max-subtraction; exp/sum + divide at end) ----
// Grid 1024: bid&7 = batch (XCD swizzle), (bid>>3)&1 = c-half (256 ch), bid>>4 = i-tile.
// Wave w: S^T j-sub (16 j) for all 4 i-subs; PV: 64 channels (ch + w*64).
__global__ __launch_bounds__(256, 3) void attn_mfma_kernel(
    const short* __restrict__ Qbf, const short* __restrict__ Kbf,
    const short* __restrict__ Vbf, const float* __restrict__ x,
    const float* __restrict__ gamma, float* __restrict__ out){
  __shared__ unsigned plds[MQ * 36];   // P~ tile: [i][64 j] bf16, row stride 36 dw
  __shared__ float lsum[4][MQ];

  const int tid  = threadIdx.x;
  const int lane = tid & 63;
  const int w    = tid >> 6;
  const int iq   = lane & 15;
  const int q    = lane >> 4;
  const int bid  = blockIdx.x;
  const int b    = bid & 7;
  const int ch   = ((bid >> 3) & 1) * 256;
  const int i0   = (bid >> 4) * MQ;

  // Q B-frags (persistent)
  bf16x8 qb[4][2];
#pragma unroll
  for (int s=0;s<4;++s){
    const short* qp = Qbf + ((size_t)b*NN + i0 + s*16 + iq)*CQ + q*8;
#pragma unroll
    for (int ks=0;ks<2;++ks) qb[s][ks] = *(const bf16x8*)(qp + ks*32);
  }

  f32x4 acc[4][4];
#pragma unroll
  for (int cs=0;cs<4;++cs)
#pragma unroll
    for (int s=0;s<4;++s) acc[cs][s] = (f32x4){0.f,0.f,0.f,0.f};
  float lpart[4] = {0.f,0.f,0.f,0.f};

  const short* Kbase = Kbf + ((size_t)b*NN + w*16 + iq)*CQ + q*8;        // A[m=j][k=o]
  const short* Vbase = Vbf + ((size_t)b*CC + ch + w*64 + iq)*NN + q*8;   // A[m=c][k=j]

  for (int jt=0; jt<NN/NJ; ++jt){
    const int j0 = jt*NJ;
    const short* kp = Kbase + (size_t)j0*CQ;
    const bf16x8 ka0 = *(const bf16x8*)kp;
    const bf16x8 ka1 = *(const bf16x8*)(kp + 32);
    f32x4 sf[4];
#pragma unroll
    for (int s=0;s<4;++s){
      sf[s] = __builtin_amdgcn_mfma_f32_16x16x32_bf16(ka0, qb[s][0], (f32x4){0.f,0.f,0.f,0.f}, 0,0,0);
      sf[s] = __builtin_amdgcn_mfma_f32_16x16x32_bf16(ka1, qb[s][1], sf[s], 0,0,0);
    }
#pragma unroll
    for (int s=0;s<4;++s){
      const float p0 = __expf(sf[s][0]);
      const float p1 = __expf(sf[s][1]);
      const float p2 = __expf(sf[s][2]);
      const float p3 = __expf(sf[s][3]);
      lpart[s] += (p0+p1) + (p2+p3);
      const int row = s*16 + iq;
      plds[row*36 + w*8 + q*2]     = pack2bf(p0, p1);
      plds[row*36 + w*8 + q*2 + 1] = pack2bf(p2, p3);
    }
    __syncthreads();
    bf16x8 pb[4][2];
#pragma unroll
    for (int s=0;s<4;++s){
      const unsigned* pr = &plds[(s*16 + iq)*36 + q*4];
      pb[s][0] = *(const bf16x8*)pr;
      pb[s][1] = *(const bf16x8*)(pr + 16);
    }
    const short* vp = Vbase + j0;
#pragma unroll
    for (int cs=0;cs<4;++cs){
      const short* vrow = vp + (size_t)cs*16*NN;
      const bf16x8 va0 = *(const bf16x8*)vrow;
      const bf16x8 va1 = *(const bf16x8*)(vrow + 32);
#pragma unroll
      for (int s=0;s<4;++s){
        acc[cs][s] = __builtin_amdgcn_mfma_f32_16x16x32_bf16(va0, pb[s][0], acc[cs][s], 0,0,0);
        acc[cs][s] = __builtin_amdgcn_mfma_f32_16x16x32_bf16(va1, pb[s][1], acc[cs][s], 0,0,0);
      }
    }
    __syncthreads();
  }

  // ---- l reduction ----
#pragma unroll
  for (int s=0;s<4;++s){
    lpart[s] += __shfl_xor(lpart[s], 16, 64);
    lpart[s] += __shfl_xor(lpart[s], 32, 64);
  }
  if (q == 0){
#pragma unroll
    for (int s=0;s<4;++s) lsum[w][s*16 + iq] = lpart[s];
  }
  __syncthreads();
  float linv[4];
#pragma unroll
  for (int s=0;s<4;++s){
    const int i = s*16 + iq;
    linv[s] = 1.0f / (lsum[0][i] + lsum[1][i] + lsum[2][i] + lsum[3][i]);
  }

  const float gam = gamma[0];
#pragma unroll
  for (int cs=0;cs<4;++cs){
#pragma unroll
    for (int s=0;s<4;++s){
      const int cb = ch + w*64 + cs*16 + q*4;
      const int i  = i0 + s*16 + iq;
#pragma unroll
      for (int r=0;r<4;++r){
        const size_t idx = ((size_t)b*CC + cb + r)*NN + i;
        out[idx] = fmaf(gam, acc[cs][s][r]*linv[s], x[idx]);
      }
    }
  }
}

extern "C" void kernel_launch(void* const* d_in, const int* in_sizes, int n_in,
                              void* d_out, int out_size, void* d_ws, size_t ws_size,
                              hipStream_t stream){
  const float* x     = (const float*)d_in[0];
  const float* Wq    = (const float*)d_in[1];
  const float* bq    = (const float*)d_in[2];
  const float* Wk    = (const float*)d_in[3];
  const float* bk    = (const float*)d_in[4];
  const float* Wv    = (const float*)d_in[5];
  const float* bv    = (const float*)d_in[6];
  const float* gamma = (const float*)d_in[7];
  float* out = (float*)d_out;

  // workspace: xT bf16 [8][4096][512] 33.6MB; Qbf/Kbf bf16 [8][4096][64] 4.2MB each;
  // Vbf bf16 [8][512][4096] 33.6MB; Wqkbf [128][512] 128KB; Wvbf [512][512] 512KB. ~76 MB
  short* xTbf = (short*)d_ws;
  short* Qbf  = xTbf + (size_t)BB*NN*CC;
  short* Kbf  = Qbf  + (size_t)BB*NN*CQ;
  short* Vbf  = Kbf  + (size_t)BB*NN*CQ;
  short* Wqkbf= Vbf  + (size_t)BB*CC*NN;
  short* Wvbf = Wqkbf + (size_t)2*CQ*CC;

  cvt_w_kernel<<<dim3(CC*CC/256), 256, 0, stream>>>(Wq, Wk, Wv, Wqkbf, Wvbf);
  cvt_x_kernel<<<dim3(NN/64, CC/64, BB), 256, 0, stream>>>(x, xTbf);
  proj_qk_mfma<<<dim3(NN/128, 1, BB), 256, 0, stream>>>(xTbf, Wqkbf, bq, bk, Qbf, Kbf);
  proj_v_mfma<<<dim3(NN/64, CC/128, BB), 256, 0, stream>>>(xTbf, Wvbf, bv, Vbf);
  attn_mfma_kernel<<<dim3(BB*NN*2/MQ), 256, 0, stream>>>(Qbf, Kbf, Vbf, x, gamma, out);
}

// Round 5
// 530.828 us; speedup vs baseline: 13.1559x; 1.1389x over previous
//
#include <hip/hip_runtime.h>
#include <hip/hip_bf16.h>
#include <cstddef>

#define BB 8
#define CC 512
#define NN 4096
#define CQ 64
#define MQ 64   // Q-rows per attn block
#define NJ 64   // j-tile

typedef short bf16x8 __attribute__((ext_vector_type(8)));
typedef float f32x4  __attribute__((ext_vector_type(4)));

// fp32 -> bf16 bits, round-to-nearest-even
static __device__ __forceinline__ unsigned bf16_bits(float f){
  unsigned u = __float_as_uint(f);
  u += 0x7fffu + ((u >> 16) & 1u);
  return u >> 16;
}
static __device__ __forceinline__ unsigned pack2bf(float lo, float hi){
  return bf16_bits(lo) | (bf16_bits(hi) << 16);
}

// ---- weights fp32 -> bf16 (Wqk packed: rows 0..63 = Wq, 64..127 = Wk) ----
__global__ __launch_bounds__(256) void cvt_w_kernel(
    const float* __restrict__ Wq, const float* __restrict__ Wk,
    const float* __restrict__ Wv,
    short* __restrict__ Wqkbf, short* __restrict__ Wvbf){
  const int i = blockIdx.x*256 + threadIdx.x;
  if (i < CQ*CC){
    Wqkbf[i]         = (short)bf16_bits(Wq[i]);
    Wqkbf[CQ*CC + i] = (short)bf16_bits(Wk[i]);
  }
  Wvbf[i] = (short)bf16_bits(Wv[i]);
}

// ---- x fp32 [b][c][n] -> xT bf16 [b][n][c] via LDS 64x64 tile ----
__global__ __launch_bounds__(256) void cvt_x_kernel(
    const float* __restrict__ x, short* __restrict__ xT){
  __shared__ float lds[64*67];
  const int tid = threadIdx.x;
  const int n0 = blockIdx.x*64, c0 = blockIdx.y*64, b = blockIdx.z;
  const int nl = tid & 63, cw = tid >> 6;
  const float* xp = x + ((size_t)b*CC + c0)*NN + n0;
#pragma unroll
  for (int i=0;i<16;++i){
    const int cl = cw*16 + i;
    lds[nl*67 + cl] = xp[(size_t)cl*NN + nl];
  }
  __syncthreads();
  short* xTp = xT + ((size_t)b*NN + n0)*CC + c0;
#pragma unroll
  for (int p=0;p<2;++p){
    const int nl2 = (tid>>3) + p*32;
    const int c8 = (tid&7)*8;
    const float* r = &lds[nl2*67 + c8];
    uint4 v;
    v.x = pack2bf(r[0], r[1]);
    v.y = pack2bf(r[2], r[3]);
    v.z = pack2bf(r[4], r[5]);
    v.w = pack2bf(r[6], r[7]);
    *(uint4*)&xTp[(size_t)nl2*CC + c8] = v;
  }
}

// ---- Q,K projection via MFMA: D[n][o] = xT . Wqk^T;  Qbf/Kbf layout [b][n][64] ----
__global__ __launch_bounds__(256) void proj_qk_mfma(
    const short* __restrict__ xT, const short* __restrict__ Wqkbf,
    const float* __restrict__ bq, const float* __restrict__ bk,
    short* __restrict__ Qbf, short* __restrict__ Kbf){
  const int tid  = threadIdx.x;
  const int lane = tid & 63;
  const int w    = tid >> 6;
  const int iq   = lane & 15;
  const int q    = lane >> 4;
  const int b    = blockIdx.z;
  const int n0w  = blockIdx.x*128 + w*32;

  f32x4 acc[2][8];
#pragma unroll
  for (int ns=0;ns<2;++ns)
#pragma unroll
    for (int os=0;os<8;++os) acc[ns][os] = (f32x4){0.f,0.f,0.f,0.f};

  const short* Abase = xT + ((size_t)b*NN + n0w + iq)*CC + q*8;
  const short* Bbase = Wqkbf + (size_t)iq*CC + q*8;

  for (int ks=0; ks<16; ++ks){
    const int k = ks*32;
    bf16x8 af[2], bf[8];
#pragma unroll
    for (int ns=0;ns<2;++ns) af[ns] = *(const bf16x8*)(Abase + (size_t)ns*16*CC + k);
#pragma unroll
    for (int os=0;os<8;++os) bf[os] = *(const bf16x8*)(Bbase + (size_t)os*16*CC + k);
#pragma unroll
    for (int ns=0;ns<2;++ns)
#pragma unroll
      for (int os=0;os<8;++os)
        acc[ns][os] = __builtin_amdgcn_mfma_f32_16x16x32_bf16(af[ns], bf[os], acc[ns][os], 0,0,0);
  }
#pragma unroll
  for (int ns=0;ns<2;++ns){
#pragma unroll
    for (int os=0;os<8;++os){
      const int o = (os&4) ? ((os-4)*16 + iq) : (os*16 + iq);
      const float bias = (os<4) ? bq[o] : bk[o];
      short* dst = (os<4) ? Qbf : Kbf;
#pragma unroll
      for (int r=0;r<4;++r){
        const int n = n0w + ns*16 + q*4 + r;
        dst[((size_t)b*NN + n)*CQ + o] = (short)bf16_bits(acc[ns][os][r] + bias);
      }
    }
  }
}

// ---- V projection via MFMA: D[c][n] = Wv . x;  Vbf layout [b][c][n] ----
__global__ __launch_bounds__(256) void proj_v_mfma(
    const short* __restrict__ xT, const short* __restrict__ Wvbf,
    const float* __restrict__ bv, short* __restrict__ Vbf){
  const int tid  = threadIdx.x;
  const int lane = tid & 63;
  const int w    = tid >> 6;
  const int iq   = lane & 15;
  const int q    = lane >> 4;
  const int b    = blockIdx.z;
  const int c0w  = blockIdx.y*128 + (w&1)*64;
  const int n0w  = blockIdx.x*64 + (w>>1)*32;

  f32x4 acc[4][2];
#pragma unroll
  for (int cs=0;cs<4;++cs)
#pragma unroll
    for (int ns=0;ns<2;++ns) acc[cs][ns] = (f32x4){0.f,0.f,0.f,0.f};

  const short* Abase = Wvbf + (size_t)(c0w + iq)*CC + q*8;
  const short* Bbase = xT + ((size_t)b*NN + n0w + iq)*CC + q*8;

  for (int ks=0; ks<16; ++ks){
    const int k = ks*32;
    bf16x8 af[4], bf[2];
#pragma unroll
    for (int cs=0;cs<4;++cs) af[cs] = *(const bf16x8*)(Abase + (size_t)cs*16*CC + k);
#pragma unroll
    for (int ns=0;ns<2;++ns) bf[ns] = *(const bf16x8*)(Bbase + (size_t)ns*16*CC + k);
#pragma unroll
    for (int cs=0;cs<4;++cs)
#pragma unroll
      for (int ns=0;ns<2;++ns)
        acc[cs][ns] = __builtin_amdgcn_mfma_f32_16x16x32_bf16(af[cs], bf[ns], acc[cs][ns], 0,0,0);
  }
#pragma unroll
  for (int cs=0;cs<4;++cs){
#pragma unroll
    for (int r=0;r<4;++r){
      const int c = c0w + cs*16 + q*4 + r;
      const float bias = bv[c];
#pragma unroll
      for (int ns=0;ns<2;++ns){
        const int n = n0w + ns*16 + iq;
        Vbf[((size_t)b*CC + c)*NN + n] = (short)bf16_bits(acc[cs][ns][r] + bias);
      }
    }
  }
}

// ---- MFMA flash attention, pipelined ----
// Grid 1024: bid&7 = batch (XCD swizzle), (bid>>3)&1 = c-half (256 ch), bid>>4 = i-tile.
// P tile LDS layout: 16-B chunk per (j-octet jo 0..7, i 0..63): dword off (jo*64+i)*4.
// Double-buffered; one lgkmcnt-only barrier per jt (global prefetches stay in flight).
__global__ __launch_bounds__(256, 2) void attn_mfma_kernel(
    const short* __restrict__ Qbf, const short* __restrict__ Kbf,
    const short* __restrict__ Vbf, const float* __restrict__ x,
    const float* __restrict__ gamma, float* __restrict__ out){
  __shared__ unsigned plds[2][2048];
  __shared__ float lsum[4][MQ];

  const int tid  = threadIdx.x;
  const int lane = tid & 63;
  const int w    = tid >> 6;
  const int iq   = lane & 15;
  const int q    = lane >> 4;
  const int bid  = blockIdx.x;
  const int b    = bid & 7;
  const int ch   = ((bid >> 3) & 1) * 256;
  const int i0   = (bid >> 4) * MQ;

  // Q B-frags (persistent)
  bf16x8 qb[4][2];
#pragma unroll
  for (int s=0;s<4;++s){
    const short* qp = Qbf + ((size_t)b*NN + i0 + s*16 + iq)*CQ + q*8;
    qb[s][0] = *(const bf16x8*)qp;
    qb[s][1] = *(const bf16x8*)(qp + 32);
  }

  f32x4 acc[4][4];
#pragma unroll
  for (int cs=0;cs<4;++cs)
#pragma unroll
    for (int s=0;s<4;++s) acc[cs][s] = (f32x4){0.f,0.f,0.f,0.f};
  float lpart[4] = {0.f,0.f,0.f,0.f};

  const short* Kbase = Kbf + ((size_t)b*NN + w*16 + iq)*CQ + q*8;        // A[m=j][k=o]
  const short* Vbase = Vbf + ((size_t)b*CC + ch + w*64 + iq)*NN + q*8;   // A[m=c][k=j]

  // LDS dword offsets: producer writes chunk jo=w*2+(q>>1), consumer reads jo=q+4*ks
  const int woff  = (w*2 + (q>>1))*256 + iq*4 + (q&1)*2;   // + s*64
  const int roff0 = q*256 + iq*4;                          // + s*64 (+1024 for ks=1)

  // K prefetch (double-buffered in regs)
  bf16x8 ka0 = *(const bf16x8*)Kbase;
  bf16x8 ka1 = *(const bf16x8*)(Kbase + 32);

#pragma unroll 2
  for (int jt=0; jt<NN/NJ; ++jt){
    const int buf = jt & 1;
    const int j0 = jt*NJ;

    // ---- issue V loads for THIS jt (consumed after barrier, ~350 cyc later) ----
    bf16x8 va[4][2];
    const short* vp = Vbase + j0;
#pragma unroll
    for (int cs=0;cs<4;++cs){
      const short* vrow = vp + (size_t)cs*16*NN;
      va[cs][0] = *(const bf16x8*)vrow;
      va[cs][1] = *(const bf16x8*)(vrow + 32);
    }
    // ---- prefetch K for jt+1 (reads past Kbf stay inside workspace; unused) ----
    const short* kp = Kbase + (size_t)(j0 + NJ)*CQ;
    bf16x8 kn0 = *(const bf16x8*)kp;
    bf16x8 kn1 = *(const bf16x8*)(kp + 32);

    // ---- S^T = K . Q^T ----
    f32x4 sf[4];
#pragma unroll
    for (int s=0;s<4;++s){
      sf[s] = __builtin_amdgcn_mfma_f32_16x16x32_bf16(ka0, qb[s][0], (f32x4){0.f,0.f,0.f,0.f}, 0,0,0);
      sf[s] = __builtin_amdgcn_mfma_f32_16x16x32_bf16(ka1, qb[s][1], sf[s], 0,0,0);
    }
    // ---- exp, l partial, pack to LDS (conflict-free chunk layout) ----
#pragma unroll
    for (int s=0;s<4;++s){
      const float p0 = __expf(sf[s][0]);
      const float p1 = __expf(sf[s][1]);
      const float p2 = __expf(sf[s][2]);
      const float p3 = __expf(sf[s][3]);
      lpart[s] += (p0+p1) + (p2+p3);
      plds[buf][woff + s*64]     = pack2bf(p0, p1);
      plds[buf][woff + s*64 + 1] = pack2bf(p2, p3);
    }
    // ---- LDS-only barrier: wait lgkmcnt(0), leave vmcnt in flight ----
    __builtin_amdgcn_s_waitcnt(0xc07f);
    __builtin_amdgcn_s_barrier();

    // ---- PV: B-frags from LDS, A = V fragments (already in flight) ----
#pragma unroll
    for (int s=0;s<4;++s){
      const bf16x8 pb0 = *(const bf16x8*)&plds[buf][roff0 + s*64];
      const bf16x8 pb1 = *(const bf16x8*)&plds[buf][roff0 + s*64 + 1024];
#pragma unroll
      for (int cs=0;cs<4;++cs){
        acc[cs][s] = __builtin_amdgcn_mfma_f32_16x16x32_bf16(va[cs][0], pb0, acc[cs][s], 0,0,0);
        acc[cs][s] = __builtin_amdgcn_mfma_f32_16x16x32_bf16(va[cs][1], pb1, acc[cs][s], 0,0,0);
      }
    }
    ka0 = kn0; ka1 = kn1;
  }

  // ---- l reduction ----
#pragma unroll
  for (int s=0;s<4;++s){
    lpart[s] += __shfl_xor(lpart[s], 16, 64);
    lpart[s] += __shfl_xor(lpart[s], 32, 64);
  }
  __syncthreads();
  if (q == 0){
#pragma unroll
    for (int s=0;s<4;++s) lsum[w][s*16 + iq] = lpart[s];
  }
  __syncthreads();
  float linv[4];
#pragma unroll
  for (int s=0;s<4;++s){
    const int i = s*16 + iq;
    linv[s] = 1.0f / (lsum[0][i] + lsum[1][i] + lsum[2][i] + lsum[3][i]);
  }

  const float gam = gamma[0];
#pragma unroll
  for (int cs=0;cs<4;++cs){
#pragma unroll
    for (int s=0;s<4;++s){
      const int cb = ch + w*64 + cs*16 + q*4;
      const int i  = i0 + s*16 + iq;
#pragma unroll
      for (int r=0;r<4;++r){
        const size_t idx = ((size_t)b*CC + cb + r)*NN + i;
        out[idx] = fmaf(gam, acc[cs][s][r]*linv[s], x[idx]);
      }
    }
  }
}

extern "C" void kernel_launch(void* const* d_in, const int* in_sizes, int n_in,
                              void* d_out, int out_size, void* d_ws, size_t ws_size,
                              hipStream_t stream){
  const float* x     = (const float*)d_in[0];
  const float* Wq    = (const float*)d_in[1];
  const float* bq    = (const float*)d_in[2];
  const float* Wk    = (const float*)d_in[3];
  const float* bk    = (const float*)d_in[4];
  const float* Wv    = (const float*)d_in[5];
  const float* bv    = (const float*)d_in[6];
  const float* gamma = (const float*)d_in[7];
  float* out = (float*)d_out;

  // workspace: xT bf16 [8][4096][512] 33.6MB; Qbf/Kbf bf16 [8][4096][64] 4.2MB each;
  // Vbf bf16 [8][512][4096] 33.6MB; Wqkbf [128][512] 128KB; Wvbf [512][512] 512KB. ~76 MB
  short* xTbf = (short*)d_ws;
  short* Qbf  = xTbf + (size_t)BB*NN*CC;
  short* Kbf  = Qbf  + (size_t)BB*NN*CQ;
  short* Vbf  = Kbf  + (size_t)BB*NN*CQ;
  short* Wqkbf= Vbf  + (size_t)BB*CC*NN;
  short* Wvbf = Wqkbf + (size_t)2*CQ*CC;

  cvt_w_kernel<<<dim3(CC*CC/256), 256, 0, stream>>>(Wq, Wk, Wv, Wqkbf, Wvbf);
  cvt_x_kernel<<<dim3(NN/64, CC/64, BB), 256, 0, stream>>>(x, xTbf);
  proj_qk_mfma<<<dim3(NN/128, 1, BB), 256, 0, stream>>>(xTbf, Wqkbf, bq, bk, Qbf, Kbf);
  proj_v_mfma<<<dim3(NN/64, CC/128, BB), 256, 0, stream>>>(xTbf, Wvbf, bv, Vbf);
  attn_mfma_kernel<<<dim3(BB*NN*2/MQ), 256, 0, stream>>>(Qbf, Kbf, Vbf, x, gamma, out);
}